// Round 1
// 330.174 us; speedup vs baseline: 1.0912x; 1.0912x over previous
//
#include <hip/hip_runtime.h>
#include <cfloat>

// VQ quantizer: pure-hi fp16 MFMA scan + packed u32 top-2 (v_med3) + in-block
// fp64 exact refine of near-ties.
//   scan dist' = cn + 256 - 2*dot_hi, dot_hi = sum qh*ch (single f16 product).
//   scan error e = 2*sum(q*r_c + r_q*c): rms ~2.4e-3, 13-sigma ~0.031 = E.
//   9-bit mask quant Q <= 0.03125 (d' < 1024 always). DELTA = 0.09375 >= 2E+Q
//   -> every potentially-wrong argmin (incl. packed ties) is flagged and
//   exactly re-decided in fp64 (dot expansion + fp64 codebook norms; the
//   per-row ||q||^2 constant cancels in argmin). dist' > 0 -> IEEE bits sort
//   as u32; low 9 mantissa bits carry the code index (tie -> smaller code).

#define DDIM 64
#define KCB  512
#define DELTA 0.09375f

typedef _Float16 f16x8 __attribute__((ext_vector_type(8)));
typedef float    f32x4 __attribute__((ext_vector_type(4)));

// ws layout (bytes)
#define WS_CN    0                         // float  cn[512]+256     [0, 2048)
#define WS_CN64  2048                      // double cn64[512]       [2048, 6144)
#define WS_FRAG  8192                      // 8 tiles * 8 KiB hi-f16 [8192, 73728)
#define WS_CBT   73728                     // float  cbT[64][512]    [73728, 204800)

__device__ __forceinline__ unsigned umed3(unsigned a, unsigned b, unsigned c) {
    unsigned d;
    asm("v_med3_u32 %0, %1, %2, %3" : "=v"(d) : "v"(a), "v"(b), "v"(c));
    return d;
}

// ---------------- K_pre ----------------
__global__ void k_pre(const float* __restrict__ cb, char* __restrict__ ws) {
    int gid = blockIdx.x * 256 + threadIdx.x;        // 16*256 = 4096
    if (gid < KCB) {
        double s = 0.0;
        for (int d = 0; d < DDIM; ++d) {
            double c = (double)cb[gid * DDIM + d];
            s += c * c;
        }
        ((float*)(ws + WS_CN))[gid] = (float)s + 256.0f;
        ((double*)(ws + WS_CN64))[gid] = s;
    }
    // hi f16 frags: 8 tiles (64 codes each) x 512 frag entries of 16 B
    {
        int t    = gid >> 9;
        int h    = gid & 511;
        int lane = h & 63;
        int subkb = h >> 6;                 // sub*2+kb
        int sub  = subkb >> 1;
        int kb   = subkb & 1;
        int code = t * 64 + sub * 16 + (lane & 15);
        int d0   = kb * 32 + ((lane >> 4) & 3) * 8;
        const float* src = cb + (size_t)code * DDIM + d0;
        union { _Float16 hv[8]; float4 f4; } hi;
        #pragma unroll
        for (int j = 0; j < 8; ++j) hi.hv[j] = (_Float16)src[j];   // RTNE
        *(float4*)(ws + WS_FRAG + (size_t)t * 8192 + (size_t)h * 16) = hi.f4;
    }
    // transposed fp32 codebook for the coalesced refine
    {
        int d  = gid >> 6;
        int kc = gid & 63;
        float tmp[8];
        #pragma unroll
        for (int j = 0; j < 8; ++j) tmp[j] = cb[(size_t)(kc * 8 + j) * DDIM + d];
        float* row = (float*)(ws + WS_CBT) + d * KCB + kc * 8;
        ((float4*)row)[0] = make_float4(tmp[0], tmp[1], tmp[2], tmp[3]);
        ((float4*)row)[1] = make_float4(tmp[4], tmp[5], tmp[6], tmp[7]);
    }
}

// ---------------- K1 ----------------
__global__ __launch_bounds__(256, 4) void k1(
    const float* __restrict__ ze, const float* __restrict__ cb,
    float* __restrict__ out, const char* __restrict__ ws)
{
    __shared__ float4 s_buf4[1024];         // 16 KiB: 2 frag tiles / out stage
    __shared__ float  s_cn[KCB];            // 2 KiB (cn+256)
    __shared__ int    s_bidx[128];
    __shared__ int    s_flist[128];
    __shared__ int    s_nflag;
    __shared__ float  s_q[DDIM];
    __shared__ double s_rv[4];
    __shared__ int    s_ri[4];

    const int tid  = threadIdx.x;
    const int wave = tid >> 6;
    const int lane = tid & 63;
    const int quad = (lane >> 4) & 3;
    const int qb_block = blockIdx.x * 128;
    const int qb_wave  = qb_block + wave * 32;

    if (tid == 0) s_nflag = 0;
    for (int i = tid; i < KCB; i += 256) s_cn[i] = ((const float*)(ws + WS_CN))[i];

    // A fragments: 2 M-tiles x 2 k-blocks, hi fp16 only (RTNE)
    union { f16x8 v; _Float16 h[8]; } qh[2][2];
    #pragma unroll
    for (int m = 0; m < 2; ++m) {
        int row = qb_wave + m * 16 + (lane & 15);
        #pragma unroll
        for (int kb = 0; kb < 2; ++kb) {
            int d0 = kb * 32 + quad * 8;
            const float4* qs = (const float4*)(ze + (size_t)row * DDIM + d0);
            float4 a = qs[0], b = qs[1];
            float f[8] = {a.x,a.y,a.z,a.w,b.x,b.y,b.z,b.w};
            #pragma unroll
            for (int j = 0; j < 8; ++j) qh[m][kb].h[j] = (_Float16)f[j];
        }
    }

    unsigned b2[2][4], s2[2][4];
    #pragma unroll
    for (int m = 0; m < 2; ++m)
        #pragma unroll
        for (int r = 0; r < 4; ++r) { b2[m][r] = 0xFFFFFFFFu; s2[m][r] = 0xFFFFFFFFu; }

    const f16x8* s_frag = (const f16x8*)s_buf4;   // 2 tiles: [0,512) and [512,1024)

    for (int rr = 0; rr < 4; ++rr) {
        __syncthreads();
        {   // stage 2 hi-tiles (16 KiB), coalesced float4
            const float4* src = (const float4*)(ws + WS_FRAG + (size_t)rr * 16384);
            #pragma unroll
            for (int j = 0; j < 4; ++j) s_buf4[j * 256 + tid] = src[j * 256 + tid];
        }
        __syncthreads();

        #pragma unroll
        for (int tt = 0; tt < 2; ++tt) {
            #pragma unroll
            for (int sub = 0; sub < 4; ++sub) {
                f32x4 a0 = {0,0,0,0}, a1 = {0,0,0,0};
                #pragma unroll
                for (int kb = 0; kb < 2; ++kb) {
                    int fi = tt * 512 + (sub * 2 + kb) * 64 + lane;
                    f16x8 bh = s_frag[fi];
                    a0 = __builtin_amdgcn_mfma_f32_16x16x32_f16(qh[0][kb].v, bh, a0, 0, 0, 0);
                    a1 = __builtin_amdgcn_mfma_f32_16x16x32_f16(qh[1][kb].v, bh, a1, 0, 0, 0);
                }
                unsigned code = (unsigned)((rr * 2 + tt) * 64 + sub * 16 + (lane & 15));
                float cnv = s_cn[code];
                #pragma unroll
                for (int r = 0; r < 4; ++r) {
                    float d0 = fmaf(a0[r], -2.0f, cnv);
                    unsigned u0 = (__float_as_uint(d0) & 0xFFFFFE00u) | code;
                    s2[0][r] = umed3(b2[0][r], s2[0][r], u0);
                    b2[0][r] = min(b2[0][r], u0);
                    float d1 = fmaf(a1[r], -2.0f, cnv);
                    unsigned u1 = (__float_as_uint(d1) & 0xFFFFFE00u) | code;
                    s2[1][r] = umed3(b2[1][r], s2[1][r], u1);
                    b2[1][r] = min(b2[1][r], u1);
                }
            }
        }
    }

    // cross-lane top-2 merge over the 16 code-columns (packed: no index shfl)
    #pragma unroll
    for (int m = 0; m < 2; ++m) {
        #pragma unroll
        for (int r = 0; r < 4; ++r) {
            unsigned b = b2[m][r], s = s2[m][r];
            #pragma unroll
            for (int mask = 1; mask < 16; mask <<= 1) {
                unsigned ob = __shfl_xor((int)b, mask);
                unsigned os = __shfl_xor((int)s, mask);
                s = min(min(s, os), max(b, ob));
                b = min(b, ob);
            }
            if ((lane & 15) == 0) {
                int lrow = wave * 32 + m * 16 + quad * 4 + r;
                s_bidx[lrow] = (int)(b & 511u);
                float fb = __uint_as_float(b & 0xFFFFFE00u);
                float fs = __uint_as_float(s & 0xFFFFFE00u);
                if (fs - fb <= DELTA) {
                    int pos = atomicAdd(&s_nflag, 1);
                    s_flist[pos & 127] = lrow;
                }
            }
        }
    }

    __syncthreads();                        // publish s_nflag / s_flist / s_bidx

    // ---- in-block fp64 exact refine (lanes-over-codes, dot expansion) ----
    int nflag = s_nflag;
    const float*  cbT  = (const float*)(ws + WS_CBT);
    const double* cn64 = (const double*)(ws + WS_CN64);
    for (int fi = 0; fi < nflag; ++fi) {
        int lrow = s_flist[fi];
        int q = qb_block + lrow;
        if (tid < DDIM) s_q[tid] = ze[(size_t)q * DDIM + tid];
        __syncthreads();
        int k0  = tid;                      // codes 0..255
        int k1c = 256 + tid;                // codes 256..511
        double a0 = 0.0, a1 = 0.0;
        #pragma unroll 8
        for (int d = 0; d < DDIM; ++d) {
            double qd = (double)s_q[d];
            a0 = fma((double)cbT[d * KCB + k0],  qd, a0);
            a1 = fma((double)cbT[d * KCB + k1c], qd, a1);
        }
        double v  = fma(-2.0, a0, cn64[k0]);  int ki = k0;   // d - ||q||^2
        double v1 = fma(-2.0, a1, cn64[k1c]);
        if (v1 < v) { v = v1; ki = k1c; }
        #pragma unroll
        for (int off = 1; off < 64; off <<= 1) {
            double ov = __shfl_xor(v, off);
            int    oi = __shfl_xor(ki, off);
            if (ov < v || (ov == v && oi < ki)) { v = ov; ki = oi; }
        }
        if (lane == 0) { s_rv[wave] = v; s_ri[wave] = ki; }
        __syncthreads();
        if (tid == 0) {
            double bv = s_rv[0]; int bk = s_ri[0];
            #pragma unroll
            for (int w = 1; w < 4; ++w)
                if (s_rv[w] < bv || (s_rv[w] == bv && s_ri[w] < bk)) { bv = s_rv[w]; bk = s_ri[w]; }
            s_bidx[lrow] = bk;
        }
        __syncthreads();
    }

    // ---- output: 4 passes x 32 rows (16 chunks each), staged via LDS ----
    const float4* cb4 = (const float4*)cb;
    #pragma unroll
    for (int p = 0; p < 4; ++p) {
        __syncthreads();
        {
            // 32 rows x 16 chunks = 512 float4 per pass, 2 per thread
            #pragma unroll
            for (int i = 0; i < 2; ++i) {
                int cc = i * 256 + tid;     // 0..511
                int rl = cc >> 4;           // row within pass (0..31)
                int sg = cc & 15;           // chunk within row
                int bi = s_bidx[p * 32 + rl];
                s_buf4[cc] = cb4[(size_t)bi * 16 + sg];
            }
        }
        __syncthreads();
        float4* dst = (float4*)(out + (size_t)(qb_block + p * 32) * DDIM);
        #pragma unroll
        for (int i = 0; i < 2; ++i) dst[i * 256 + tid] = s_buf4[i * 256 + tid];
    }
}

extern "C" void kernel_launch(void* const* d_in, const int* in_sizes, int n_in,
                              void* d_out, int out_size, void* d_ws, size_t ws_size,
                              hipStream_t stream) {
    const float* ze = (const float*)d_in[0];
    const float* cb = (const float*)d_in[1];
    float* out = (float*)d_out;
    char* ws = (char*)d_ws;

    const int nq = in_sizes[0] / DDIM;                 // 524288
    k_pre<<<16, 256, 0, stream>>>(cb, ws);
    k1<<<nq / 128, 256, 0, stream>>>(ze, cb, out, ws);
}

// Round 2
// 316.230 us; speedup vs baseline: 1.1393x; 1.0441x over previous
//
#include <hip/hip_runtime.h>
#include <cfloat>

// VQ quantizer: pure-hi fp16 MFMA scan + packed u32 top-2 (v_med3) + wave-
// parallel fp64 exact refine of near-ties.
//   scan dist' = cn + 256 - 2*dot_hi, dot_hi = sum qh*ch (single f16 product).
//   scan error e = 2*sum(q*r_c + r_q*c): rms ~2.4e-3, 13-sigma ~0.031 = E.
//   9-bit mask quant Q <= 0.03125 (d' < 1024 always). DELTA = 0.09375 >= 2E+Q
//   -> every potentially-wrong argmin (incl. packed ties) is flagged and
//   exactly re-decided in fp64 (dot expansion + fp64 codebook norms; the
//   per-row ||q||^2 constant cancels in argmin). dist' > 0 -> IEEE bits sort
//   as u32; low 9 mantissa bits carry the code index (tie -> smaller code).
// Pipeline: one-tile (8 KiB) LDS double-buffer filled by global_load_lds
// issued one tile ahead; ONE __syncthreads per tile (its vmcnt drain lands
// the prefetch). Epilogue + refine are barrier-free.

#define DDIM 64
#define KCB  512
#define DELTA 0.09375f

typedef _Float16 f16x8 __attribute__((ext_vector_type(8)));
typedef float    f32x4 __attribute__((ext_vector_type(4)));

// ws layout (bytes)
#define WS_CN    0                         // float  cn[512]+256     [0, 2048)
#define WS_CN64  2048                      // double cn64[512]       [2048, 6144)
#define WS_FRAG  8192                      // 8 tiles * 8 KiB hi-f16 [8192, 73728)
#define WS_CBT   73728                     // float  cbT[64][512]    [73728, 204800)

__device__ __forceinline__ unsigned umed3(unsigned a, unsigned b, unsigned c) {
    unsigned d;
    asm("v_med3_u32 %0, %1, %2, %3" : "=v"(d) : "v"(a), "v"(b), "v"(c));
    return d;
}

typedef const unsigned int __attribute__((address_space(1))) as1_uint;
typedef unsigned int __attribute__((address_space(3))) as3_uint;

__device__ __forceinline__ void gload16(const void* g, void* l) {
    __builtin_amdgcn_global_load_lds((as1_uint*)g, (as3_uint*)l, 16, 0, 0);
}

// ---------------- K_pre ----------------
__global__ void k_pre(const float* __restrict__ cb, char* __restrict__ ws) {
    int gid = blockIdx.x * 256 + threadIdx.x;        // 16*256 = 4096
    if (gid < KCB) {
        double s0 = 0.0, s1 = 0.0, s2 = 0.0, s3 = 0.0;
        for (int d = 0; d < DDIM; d += 4) {
            double c0 = (double)cb[gid * DDIM + d + 0];
            double c1 = (double)cb[gid * DDIM + d + 1];
            double c2 = (double)cb[gid * DDIM + d + 2];
            double c3 = (double)cb[gid * DDIM + d + 3];
            s0 = fma(c0, c0, s0); s1 = fma(c1, c1, s1);
            s2 = fma(c2, c2, s2); s3 = fma(c3, c3, s3);
        }
        double s = (s0 + s1) + (s2 + s3);
        ((float*)(ws + WS_CN))[gid] = (float)s + 256.0f;
        ((double*)(ws + WS_CN64))[gid] = s;
    }
    // hi f16 frags: 8 tiles (64 codes each) x 512 frag entries of 16 B
    {
        int t    = gid >> 9;
        int h    = gid & 511;
        int lane = h & 63;
        int subkb = h >> 6;                 // sub*2+kb
        int sub  = subkb >> 1;
        int kb   = subkb & 1;
        int code = t * 64 + sub * 16 + (lane & 15);
        int d0   = kb * 32 + ((lane >> 4) & 3) * 8;
        const float* src = cb + (size_t)code * DDIM + d0;
        union { _Float16 hv[8]; float4 f4; } hi;
        #pragma unroll
        for (int j = 0; j < 8; ++j) hi.hv[j] = (_Float16)src[j];   // RTNE
        *(float4*)(ws + WS_FRAG + (size_t)t * 8192 + (size_t)h * 16) = hi.f4;
    }
    // transposed fp32 codebook for the coalesced refine
    {
        int d  = gid >> 6;
        int kc = gid & 63;
        float tmp[8];
        #pragma unroll
        for (int j = 0; j < 8; ++j) tmp[j] = cb[(size_t)(kc * 8 + j) * DDIM + d];
        float* row = (float*)(ws + WS_CBT) + d * KCB + kc * 8;
        ((float4*)row)[0] = make_float4(tmp[0], tmp[1], tmp[2], tmp[3]);
        ((float4*)row)[1] = make_float4(tmp[4], tmp[5], tmp[6], tmp[7]);
    }
}

// ---------------- K1 ----------------
__global__ __launch_bounds__(256, 6) void k1(
    const float* __restrict__ ze, const float* __restrict__ cb,
    float* __restrict__ out, const char* __restrict__ ws)
{
    __shared__ f16x8 s_frag[1024];          // 16 KiB: 2 x one-tile buffers
    __shared__ float s_cn[KCB];             // 2 KiB (cn+256)
    __shared__ int   s_bidx[128];
    __shared__ int   s_flist[128];
    __shared__ int   s_nflag;

    const int tid  = threadIdx.x;
    const int wave = tid >> 6;
    const int lane = tid & 63;
    const int quad = (lane >> 4) & 3;
    const int qb_block = blockIdx.x * 128;
    const int qb_wave  = qb_block + wave * 32;

    if (tid == 0) s_nflag = 0;
    for (int i = tid; i < KCB; i += 256) s_cn[i] = ((const float*)(ws + WS_CN))[i];

    // issue tile 0 -> buffer 0 (direct global->LDS, lands at first barrier)
    {
        const char* src = ws + WS_FRAG;
        char* dst = (char*)s_frag;
        #pragma unroll
        for (int j = 0; j < 2; ++j)
            gload16(src + j * 4096 + wave * 1024 + lane * 16,
                    dst + j * 4096 + wave * 1024);
    }

    // A fragments: 2 M-tiles x 2 k-blocks, hi fp16 only (RTNE)
    union { f16x8 v; _Float16 h[8]; } qh[2][2];
    #pragma unroll
    for (int m = 0; m < 2; ++m) {
        int row = qb_wave + m * 16 + (lane & 15);
        #pragma unroll
        for (int kb = 0; kb < 2; ++kb) {
            int d0 = kb * 32 + quad * 8;
            const float4* qs = (const float4*)(ze + (size_t)row * DDIM + d0);
            float4 a = qs[0], b = qs[1];
            float f[8] = {a.x,a.y,a.z,a.w,b.x,b.y,b.z,b.w};
            #pragma unroll
            for (int j = 0; j < 8; ++j) qh[m][kb].h[j] = (_Float16)f[j];
        }
    }

    unsigned b2[2][4], s2[2][4];
    #pragma unroll
    for (int m = 0; m < 2; ++m)
        #pragma unroll
        for (int r = 0; r < 4; ++r) { b2[m][r] = 0xFFFFFFFFu; s2[m][r] = 0xFFFFFFFFu; }

    __syncthreads();                        // tile 0 + s_cn ready

    for (int t = 0; t < 8; ++t) {
        int cur = t & 1;
        if (t < 7) {                        // prefetch tile t+1 -> other buffer
            const char* src = ws + WS_FRAG + (size_t)(t + 1) * 8192;
            char* dst = (char*)s_frag + (cur ^ 1) * 8192;
            #pragma unroll
            for (int j = 0; j < 2; ++j)
                gload16(src + j * 4096 + wave * 1024 + lane * 16,
                        dst + j * 4096 + wave * 1024);
        }
        #pragma unroll
        for (int sub = 0; sub < 4; ++sub) {
            f32x4 a0 = {0,0,0,0}, a1 = {0,0,0,0};
            #pragma unroll
            for (int kb = 0; kb < 2; ++kb) {
                int fi = cur * 512 + (sub * 2 + kb) * 64 + lane;
                f16x8 bh = s_frag[fi];
                a0 = __builtin_amdgcn_mfma_f32_16x16x32_f16(qh[0][kb].v, bh, a0, 0, 0, 0);
                a1 = __builtin_amdgcn_mfma_f32_16x16x32_f16(qh[1][kb].v, bh, a1, 0, 0, 0);
            }
            unsigned code = (unsigned)(t * 64 + sub * 16 + (lane & 15));
            float cnv = s_cn[code];
            #pragma unroll
            for (int r = 0; r < 4; ++r) {
                float d0 = fmaf(a0[r], -2.0f, cnv);
                unsigned u0 = (__float_as_uint(d0) & 0xFFFFFE00u) | code;
                s2[0][r] = umed3(b2[0][r], s2[0][r], u0);
                b2[0][r] = min(b2[0][r], u0);
                float d1 = fmaf(a1[r], -2.0f, cnv);
                unsigned u1 = (__float_as_uint(d1) & 0xFFFFFE00u) | code;
                s2[1][r] = umed3(b2[1][r], s2[1][r], u1);
                b2[1][r] = min(b2[1][r], u1);
            }
        }
        __syncthreads();                    // drains vmcnt: tile t+1 landed;
                                            // all waves done reading buf cur
    }

    // cross-lane top-2 merge over the 16 code-columns (packed: no index shfl)
    #pragma unroll
    for (int m = 0; m < 2; ++m) {
        #pragma unroll
        for (int r = 0; r < 4; ++r) {
            unsigned b = b2[m][r], s = s2[m][r];
            #pragma unroll
            for (int mask = 1; mask < 16; mask <<= 1) {
                unsigned ob = __shfl_xor((int)b, mask);
                unsigned os = __shfl_xor((int)s, mask);
                s = min(min(s, os), max(b, ob));
                b = min(b, ob);
            }
            if ((lane & 15) == 0) {
                int lrow = wave * 32 + m * 16 + quad * 4 + r;
                s_bidx[lrow] = (int)(b & 511u);
                float fb = __uint_as_float(b & 0xFFFFFE00u);
                float fs = __uint_as_float(s & 0xFFFFFE00u);
                if (fs - fb <= DELTA) {
                    int pos = atomicAdd(&s_nflag, 1);
                    s_flist[pos & 127] = lrow;
                }
            }
        }
    }

    __syncthreads();                        // publish s_nflag / s_flist / s_bidx

    // ---- wave-parallel fp64 exact refine (one wave per flagged row) ----
    int nflag = s_nflag;
    const float*  cbT  = (const float*)(ws + WS_CBT);
    const double* cn64 = (const double*)(ws + WS_CN64);
    for (int fi = wave; fi < nflag; fi += 4) {
        int lrow = s_flist[fi];
        int q = qb_block + lrow;
        float qv = ze[(size_t)q * DDIM + lane];          // lane d holds q[d]
        double acc[8] = {0,0,0,0,0,0,0,0};               // codes lane*8+j
        #pragma unroll 8
        for (int d = 0; d < DDIM; ++d) {
            double qd = (double)__shfl(qv, d);
            const float4* c4 = (const float4*)(cbT + d * KCB + lane * 8);
            float4 x = c4[0], y = c4[1];
            acc[0] = fma((double)x.x, qd, acc[0]);
            acc[1] = fma((double)x.y, qd, acc[1]);
            acc[2] = fma((double)x.z, qd, acc[2]);
            acc[3] = fma((double)x.w, qd, acc[3]);
            acc[4] = fma((double)y.x, qd, acc[4]);
            acc[5] = fma((double)y.y, qd, acc[5]);
            acc[6] = fma((double)y.z, qd, acc[6]);
            acc[7] = fma((double)y.w, qd, acc[7]);
        }
        double v = DBL_MAX; int ki = 0;
        #pragma unroll
        for (int j = 0; j < 8; ++j) {                    // j asc -> smaller code wins ties
            int k = lane * 8 + j;
            double dj = fma(-2.0, acc[j], cn64[k]);      // d' - ||q||^2
            if (dj < v) { v = dj; ki = k; }
        }
        #pragma unroll
        for (int off = 1; off < 64; off <<= 1) {
            double ov = __shfl_xor(v, off);
            int    oi = __shfl_xor(ki, off);
            if (ov < v || (ov == v && oi < ki)) { v = ov; ki = oi; }
        }
        if (lane == 0) s_bidx[lrow] = ki;
    }

    __syncthreads();                        // s_bidx final

    // ---- output: direct gather cb[bidx] -> out, no LDS staging ----
    const float4* cb4  = (const float4*)cb;
    float4*       out4 = (float4*)out + (size_t)qb_block * 16;
    #pragma unroll
    for (int i = 0; i < 8; ++i) {
        int cc  = i * 256 + tid;            // 0..2047
        int row = cc >> 4;                  // 0..127
        int sg  = cc & 15;
        int bi  = s_bidx[row];
        out4[(size_t)row * 16 + sg] = cb4[(size_t)bi * 16 + sg];
    }
}

extern "C" void kernel_launch(void* const* d_in, const int* in_sizes, int n_in,
                              void* d_out, int out_size, void* d_ws, size_t ws_size,
                              hipStream_t stream) {
    const float* ze = (const float*)d_in[0];
    const float* cb = (const float*)d_in[1];
    float* out = (float*)d_out;
    char* ws = (char*)d_ws;

    const int nq = in_sizes[0] / DDIM;                 // 524288
    k_pre<<<16, 256, 0, stream>>>(cb, ws);
    k1<<<nq / 128, 256, 0, stream>>>(ze, cb, out, ws);
}